// Round 13
// baseline (378.751 us; speedup 1.0000x reference)
//
#include <hip/hip_runtime.h>

// ---------------------------------------------------------------------------
// MLPDeepSet fused fp16-MFMA implementation for gfx950.
//
//  k_prep : convert x->fp16, prepack all weights into MFMA A-fragment order.
//  k_atoms: AP = x @ W_in[0:256] + b_in ; BP = x @ W_in[256:512]  (fp16 out)
//  k_edges: R13 counted-vmcnt pipeline (m201-style). 128-edge block,
//           8 waves = 2ge x 4gn, acc[4][4] (64 AGPR). Weights flow
//           global->LDS via global_load_lds into a 4-slot ring (16 KB
//           K-slices), 3 slices in flight, s_waitcnt vmcnt(4) counted —
//           never drained mid-stream. Per step: {ds_read A,B; stage(t+3);
//           vmcnt(4); lgkmcnt(0); sched_barrier; s_barrier; 16 MFMA}.
//           h single-buffered 64 KB (in-place epilogue safe: layer's
//           B-reads all drain at its last step barrier). Biases in LDS so
//           vmcnt counts stay exact. LDS ~139 KB -> 1 block/CU.
// ---------------------------------------------------------------------------

typedef _Float16 f16x8 __attribute__((ext_vector_type(8)));
typedef _Float16 f16x4 __attribute__((ext_vector_type(4)));
typedef __fp16   fp16v2 __attribute__((ext_vector_type(2)));
typedef float    f32x4 __attribute__((ext_vector_type(4)));
typedef unsigned int u32x4 __attribute__((ext_vector_type(4)));
typedef unsigned int u32x2 __attribute__((ext_vector_type(2)));

union H8 { f16x8 v; _Float16 h[8]; u32x4 u; };
union H4 { f16x4 v; u32x2 u; };
union H2 { fp16v2 h; unsigned int u; };

#define MFMA16(a, b, c) __builtin_amdgcn_mfma_f32_16x16x32_f16((a), (b), (c), 0, 0, 0)

#define LOG2E 1.44269504088896340736f

__device__ inline void gload_lds16(const void* g, void* l) {
  __builtin_amdgcn_global_load_lds(
      (const __attribute__((address_space(1))) void*)g,
      (__attribute__((address_space(3))) void*)l, 16, 0, 0);
}

// workspace byte offsets
#define WS_WP   0u          // 6 layers  : 6*65536 halves = 786432 B
#define WS_WPI  786432u     // 65536 halves = 131072 B
#define WS_WPJ  917504u     // 65536 halves = 131072 B
#define WS_WPR  1048576u    // 8192 halves  = 16384 B   (rbf+d, K padded to 32)
#define WS_XH   1064960u    // 2097152 halves = 4194304 B
#define WS_AP   5259264u    // 2097152 fp16 = 4194304 B
#define WS_BP   9453568u    // 2097152 fp16 = 4194304 B
// total 13647872 B

// ---------------------------------------------------------------------------
__global__ __launch_bounds__(256) void k_prep(
    const float* __restrict__ x, const float* __restrict__ W_in,
    const float* __restrict__ Ws, const float* __restrict__ b_out,
    _Float16* __restrict__ wp, _Float16* __restrict__ wpi,
    _Float16* __restrict__ wpj, _Float16* __restrict__ wpr,
    _Float16* __restrict__ xh, float* __restrict__ out)
{
  int i = blockIdx.x * 256 + threadIdx.x;
  if (i < 2097152) { xh[i] = (_Float16)x[i]; return; }
  i -= 2097152;
  if (i < 393216) {  // 6 hidden layers, A-fragment order (A = W^T)
    int m = i >> 16, r = i & 65535;
    int j = r & 7, lane = (r >> 3) & 63, ks = (r >> 9) & 7, nt = (r >> 12) & 15;
    int k = ks * 32 + (lane >> 4) * 8 + j, n = nt * 16 + (lane & 15);
    wp[i] = (_Float16)Ws[(m * 256 + k) * 256 + n];
    return;
  }
  i -= 393216;
  if (i < 65536) {   // W_in rows 0..255 (x_i part)
    int j = i & 7, lane = (i >> 3) & 63, ks = (i >> 9) & 7, nt = (i >> 12) & 15;
    int k = ks * 32 + (lane >> 4) * 8 + j, n = nt * 16 + (lane & 15);
    wpi[i] = (_Float16)W_in[k * 256 + n];
    return;
  }
  i -= 65536;
  if (i < 65536) {   // W_in rows 256..511 (x_j part)
    int j = i & 7, lane = (i >> 3) & 63, ks = (i >> 9) & 7, nt = (i >> 12) & 15;
    int k = ks * 32 + (lane >> 4) * 8 + j, n = nt * 16 + (lane & 15);
    wpj[i] = (_Float16)W_in[(256 + k) * 256 + n];
    return;
  }
  i -= 65536;
  if (i < 8192) {    // rbf rows 512..531 + d row 532, K padded 20+1 -> 32
    int j = i & 7, lane = (i >> 3) & 63, nt = (i >> 9) & 15;
    int k = (lane >> 4) * 8 + j, n = nt * 16 + (lane & 15);
    float v = 0.0f;
    if (k < 20)       v = W_in[(512 + k) * 256 + n];
    else if (k == 20) v = W_in[532 * 256 + n];
    wpr[i] = (_Float16)v;
    return;
  }
  i -= 8192;
  if (i < 8192) out[i] = b_out[0];
}

// ---------------------------------------------------------------------------
// AP/BP: M=8192 atoms, K=256, N=256, fp16 packed output. BM=64 atoms/block,
// 4 waves (one 64-n slice each). blockIdx.y selects AP (with b_in) or BP.
__global__ __launch_bounds__(256) void k_atoms(
    const _Float16* __restrict__ xh,
    const _Float16* __restrict__ wpi, const _Float16* __restrict__ wpj,
    const float* __restrict__ b_in,
    _Float16* __restrict__ AP, _Float16* __restrict__ BP)
{
  const int tid = threadIdx.x;
  const int l = tid & 63, w = tid >> 6;
  const int g = l >> 4, c = l & 15;
  const int which = blockIdx.y;
  const _Float16* wpx = which ? wpj : wpi;
  _Float16* outp = which ? BP : AP;
  const int abase = blockIdx.x * 64;

  f32x4 acc[4][4];
#pragma unroll
  for (int nf = 0; nf < 4; ++nf)
#pragma unroll
    for (int at = 0; at < 4; ++at) acc[nf][at] = (f32x4)0.0f;

#pragma unroll
  for (int ks = 0; ks < 8; ++ks) {
    f16x8 a[4];
#pragma unroll
    for (int nf = 0; nf < 4; ++nf) {
      H8 t; t.u = *(const u32x4*)(wpx + (((w * 4 + nf) * 8 + ks) * 64 + l) * 8);
      a[nf] = t.v;
    }
#pragma unroll
    for (int at = 0; at < 4; ++at) {
      H8 b; b.u = *(const u32x4*)(xh + (abase + at * 16 + c) * 256 + ks * 32 + g * 8);
#pragma unroll
      for (int nf = 0; nf < 4; ++nf)
        acc[nf][at] = MFMA16(a[nf], b.v, acc[nf][at]);
    }
  }

#pragma unroll
  for (int nf = 0; nf < 4; ++nf) {
    const int n = w * 64 + nf * 16 + g * 4;
    f32x4 bias = (f32x4)0.0f;
    if (!which) bias = *(const f32x4*)(b_in + n);
#pragma unroll
    for (int at = 0; at < 4; ++at) {
      const int atom = abase + at * 16 + c;
      const f32x4 t = acc[nf][at] + bias;
      H2 lo, hi;
      lo.h = __builtin_amdgcn_cvt_pkrtz(t[0], t[1]);
      hi.h = __builtin_amdgcn_cvt_pkrtz(t[2], t[3]);
      u32x2 q; q[0] = lo.u; q[1] = hi.u;
      *(u32x2*)(outp + atom * 256 + n) = q;
    }
  }
}

// ---------------------------------------------------------------------------
// R13 counted-vmcnt fused edge pipeline.
// 128 edges/block, 512 threads = 8 waves = 2 edge-groups(64e) x 4 n-groups
// (64f); acc[4][4] (64 AGPR). h [128e][256f] fp16 swizzled, 64 KB, single.
// Weight K-slices (32k x 256n = 16 KB) in a 4-slot LDS ring, staged by
// global_load_lds (wave w stages frags {2w,2w+1}); 3 slices in flight,
// counted s_waitcnt vmcnt(4). Biases in LDS (keep vmcnt exact).
__global__ __launch_bounds__(512, 2) void k_edges(
    const _Float16* __restrict__ AP, const _Float16* __restrict__ BP,
    const int* __restrict__ idx_i, const int* __restrict__ idx_j,
    const float* __restrict__ d_ij,
    const _Float16* __restrict__ wp, const _Float16* __restrict__ wpr,
    const float* __restrict__ bs, const float* __restrict__ W_out,
    float* __restrict__ out)
{
  __shared__ __align__(16) char hb[65536];
  __shared__ __align__(16) char wbuf[65536];     // 4 x 16 KB K-slice ring
  __shared__ float b_lds[1536];
  __shared__ float d_lds[128];
  __shared__ int   ii_lds[128];
  __shared__ int   jj_lds[128];
  __shared__ float oacc[128];

  const int tid = threadIdx.x;
  const int l = tid & 63, w = tid >> 6;
  const int ge = w >> 2, gn = w & 3;
  const int g = l >> 4, c = l & 15;
  const int ebase = blockIdx.x * 128;
  const int we = ge * 64;         // wave's edge base
  const int nb = gn * 64;         // wave's feature base
  const int sw = (c << 4) | ((c & 1) << 8);  // row swizzle

  if (tid < 128) {
    ii_lds[tid] = idx_i[ebase + tid];
    jj_lds[tid] = idx_j[ebase + tid];
    d_lds[tid]  = d_ij[ebase + tid];
    oacc[tid]   = 0.0f;
  }
  b_lds[tid]        = bs[tid];
  b_lds[tid + 512]  = bs[tid + 512];
  b_lds[tid + 1024] = bs[tid + 1024];
  __syncthreads();

  f32x4 acc[4][4];  // [nf][et] : 64 features x 64 edges

  // ---- input layer: rbf(20)+d via one K=32 MFMA step ----
  {
    const float STEP = 15.0f / 19.0f;
    const float C2 = (-0.5f / (STEP * STEP)) * LOG2E;
    f16x8 afr[4];
#pragma unroll
    for (int nf = 0; nf < 4; ++nf) {
      H8 t; t.u = *(const u32x4*)(wpr + ((gn * 4 + nf) * 64 + l) * 8);
      afr[nf] = t.v;
    }
#pragma unroll
    for (int et = 0; et < 4; ++et) {
      const float d = d_lds[we + et * 16 + c];
      H8 bb;
#pragma unroll
      for (int j = 0; j < 8; ++j) {
        const int k = g * 8 + j;
        float v = 0.0f;
        if (k < 20)       { const float df = d - (float)k * STEP; v = __builtin_amdgcn_exp2f(C2 * df * df); }
        else if (k == 20) { v = d; }
        bb.h[j] = (_Float16)v;
      }
      const f32x4 z = (f32x4)0.0f;
#pragma unroll
      for (int nf = 0; nf < 4; ++nf)
        acc[nf][et] = MFMA16(afr[nf], bb.v, z);
    }
  }
  // h0 = pack(rbf acc) + AP[idx_i] + BP[idx_j]  (fp16 pk_add) -> hb
#pragma unroll
  for (int nf = 0; nf < 4; ++nf) {
    const int n = nb + nf * 16 + g * 4;
    const int obase = n * 2;
#pragma unroll
    for (int et = 0; et < 4; ++et) {
      const int el = we + et * 16 + c;
      H4 pa, pb, s;
      pa.u = *(const u32x2*)(AP + ii_lds[el] * 256 + n);
      pb.u = *(const u32x2*)(BP + jj_lds[el] * 256 + n);
      H2 lo, hi;
      lo.h = __builtin_amdgcn_cvt_pkrtz(acc[nf][et][0], acc[nf][et][1]);
      hi.h = __builtin_amdgcn_cvt_pkrtz(acc[nf][et][2], acc[nf][et][3]);
      s.u[0] = lo.u; s.u[1] = hi.u;
      s.v = s.v + pa.v + pb.v;
      *(u32x2*)(hb + el * 512 + (obase ^ sw)) = s.u;
    }
  }

  // stage(u): copy K-slice u (layer u>>3, ks u&7) into ring slot u&3.
  // wave w stages fragments {2w, 2w+1}: 2 vmem instrs/wave.
  auto stage = [&](int u) {
    const char* srcbase = (const char*)wp + (u >> 3) * 131072;
    char* dst = wbuf + (u & 3) * 16384;
    const int kst = u & 7;
#pragma unroll
    for (int q = 0; q < 2; ++q) {
      const int f = w * 2 + q;
      gload_lds16(srcbase + (f * 8 + kst) * 1024 + l * 16, dst + f * 1024);
    }
  };
  stage(0);
  stage(1);
  stage(2);
  asm volatile("s_waitcnt vmcnt(4)" ::: "memory");   // slice 0 landed
  asm volatile("s_waitcnt lgkmcnt(0)" ::: "memory"); // h0 writes drained
  __builtin_amdgcn_s_barrier();

#pragma unroll 1
  for (int t = 0; t < 48; ++t) {
    const int ks = t & 7, ly = t >> 3;
    if (ks == 0) {  // acc = bias(ly), read from LDS (lgkm, not vmcnt)
#pragma unroll
      for (int nf = 0; nf < 4; ++nf) {
        const f32x4 bias = *(const f32x4*)(&b_lds[ly * 256 + nb + nf * 16 + g * 4]);
#pragma unroll
        for (int et = 0; et < 4; ++et) acc[nf][et] = bias;
      }
    }
    // issue reads for THIS step (slice t guaranteed staged by barrier t-1)
    f16x8 a[4];
    const char* wsl = wbuf + (t & 3) * 16384;
#pragma unroll
    for (int nf = 0; nf < 4; ++nf) {
      H8 ta; ta.u = *(const u32x4*)(wsl + (gn * 4 + nf) * 1024 + l * 16);
      a[nf] = ta.v;
    }
    H8 b4[4];
    const int o = (ks * 64 + g * 16) ^ sw;
#pragma unroll
    for (int et = 0; et < 4; ++et)
      b4[et].u = *(const u32x4*)(hb + (we + et * 16 + c) * 512 + o);
    // issue stage for t+3 (targets slot read at t-1 -> safe after bar t-1)
    if (t + 3 < 48) stage(t + 3);
    // counted waits: stage(t+1) complete (<=4 outstanding of {t+1,t+2,t+3})
    if (t <= 44) asm volatile("s_waitcnt vmcnt(4)" ::: "memory");
    else         asm volatile("s_waitcnt vmcnt(0)" ::: "memory");
    asm volatile("s_waitcnt lgkmcnt(0)" ::: "memory");
    __builtin_amdgcn_sched_barrier(0);
    __builtin_amdgcn_s_barrier();
    __builtin_amdgcn_s_setprio(1);
#pragma unroll
    for (int et = 0; et < 4; ++et)
#pragma unroll
      for (int nf = 0; nf < 4; ++nf)
        acc[nf][et] = MFMA16(a[nf], b4[et].v, acc[nf][et]);
    __builtin_amdgcn_s_setprio(0);
    if (ks == 7 && ly < 5) {
      // epilogue: all waves' layer-ly B-reads drained at this step's barrier
      // -> in-place hb overwrite is safe.
#pragma unroll
      for (int nf = 0; nf < 4; ++nf) {
        const int n = nb + nf * 16 + g * 4;
        const int obase = n * 2;
#pragma unroll
        for (int et = 0; et < 4; ++et) {
          f32x4 v = acc[nf][et];
#pragma unroll
          for (int j = 0; j < 4; ++j) {
            const float e = __builtin_amdgcn_exp2f(v[j] * -LOG2E);
            v[j] = v[j] * __builtin_amdgcn_rcpf(1.0f + e);   // fast SiLU
          }
          const int el = we + et * 16 + c;
          H2 lo, hi;
          lo.h = __builtin_amdgcn_cvt_pkrtz(v[0], v[1]);
          hi.h = __builtin_amdgcn_cvt_pkrtz(v[2], v[3]);
          u32x2 q; q[0] = lo.u; q[1] = hi.u;
          *(u32x2*)(hb + el * 512 + (obase ^ sw)) = q;
        }
      }
      asm volatile("s_waitcnt lgkmcnt(0)" ::: "memory");
      __builtin_amdgcn_s_barrier();   // h(ly+1) visible before next reads
    }
  }

  // layer-6 accs live: fold W_out dot immediately
  float sum[4];
#pragma unroll
  for (int et = 0; et < 4; ++et) sum[et] = 0.0f;
#pragma unroll
  for (int nf = 0; nf < 4; ++nf) {
    const int n = nb + nf * 16 + g * 4;
    const f32x4 wo = *(const f32x4*)(W_out + n);
#pragma unroll
    for (int et = 0; et < 4; ++et) {
      const f32x4 v = acc[nf][et];
      sum[et] += v[0] * wo[0] + v[1] * wo[1] + v[2] * wo[2] + v[3] * wo[3];
    }
  }
#pragma unroll
  for (int et = 0; et < 4; ++et) {
    float s = sum[et];
    s += __shfl_xor(s, 16, 64);
    s += __shfl_xor(s, 32, 64);
    if (l < 16) atomicAdd(&oacc[we + et * 16 + l], s);
  }
  __syncthreads();
  if (tid < 128) atomicAdd(out + ii_lds[tid], oacc[tid]);
}

// ---------------------------------------------------------------------------
extern "C" void kernel_launch(void* const* d_in, const int* in_sizes, int n_in,
                              void* d_out, int out_size, void* d_ws, size_t ws_size,
                              hipStream_t stream) {
  (void)in_sizes; (void)n_in; (void)out_size; (void)ws_size;
  const float* x     = (const float*)d_in[0];
  const float* d_ij  = (const float*)d_in[1];
  const int*   idx_i = (const int*)d_in[2];
  const int*   idx_j = (const int*)d_in[3];
  const float* W_in  = (const float*)d_in[4];
  const float* b_in  = (const float*)d_in[5];
  const float* Ws    = (const float*)d_in[6];
  const float* bs    = (const float*)d_in[7];
  const float* W_out = (const float*)d_in[8];
  const float* b_out = (const float*)d_in[9];
  float* out = (float*)d_out;
  char* ws = (char*)d_ws;

  _Float16* wp  = (_Float16*)(ws + WS_WP);
  _Float16* wpi = (_Float16*)(ws + WS_WPI);
  _Float16* wpj = (_Float16*)(ws + WS_WPJ);
  _Float16* wpr = (_Float16*)(ws + WS_WPR);
  _Float16* xh  = (_Float16*)(ws + WS_XH);
  _Float16* AP  = (_Float16*)(ws + WS_AP);
  _Float16* BP  = (_Float16*)(ws + WS_BP);

  hipLaunchKernelGGL(k_prep, dim3(10305), dim3(256), 0, stream,
                     x, W_in, Ws, b_out, wp, wpi, wpj, wpr, xh, out);
  hipLaunchKernelGGL(k_atoms, dim3(128, 2), dim3(256), 0, stream,
                     xh, wpi, wpj, b_in, AP, BP);
  hipLaunchKernelGGL(k_edges, dim3(2048), dim3(512), 0, stream,
                     AP, BP, idx_i, idx_j, d_ij, wp, wpr, bs, W_out, out);
}

// Round 14
// 378.090 us; speedup vs baseline: 1.0017x; 1.0017x over previous
//
#include <hip/hip_runtime.h>

// ---------------------------------------------------------------------------
// MLPDeepSet fused fp16-MFMA implementation for gfx950.
//
//  k_prep : convert x->fp16, prepack weights into 32x32x16 MFMA A-fragment
//           order (hidden layers + rbf); 16x16 order for k_atoms.
//  k_atoms: AP = x @ W_in[0:256] + b_in ; BP = x @ W_in[256:512]  (fp16 out)
//  k_edges: R14 = R4 frame ported to v_mfma_f32_32x32x16_f16 (2382 vs 2075
//           TF pipe rate, half the MFMA issue slots). 128-edge block, 8
//           waves = 2ge x 4gn; wave tile 64f x 64e as 2x2 tiles of 32x32,
//           acc = 4 x f32x16 (64 AGPR). 2 barriers/layer, 2 blocks/CU.
//           A-frag: row=l&31, k=(l>>5)*8+j. C/D: col(edge)=l&31,
//           row(feat)=q*8+4*(l>>5)+i (m74/m101). Swizzle: byte^=(l&31)<<4.
// ---------------------------------------------------------------------------

typedef _Float16 f16x8 __attribute__((ext_vector_type(8)));
typedef _Float16 f16x4 __attribute__((ext_vector_type(4)));
typedef __fp16   fp16v2 __attribute__((ext_vector_type(2)));
typedef float    f32x4 __attribute__((ext_vector_type(4)));
typedef float    f32x16 __attribute__((ext_vector_type(16)));
typedef unsigned int u32x4 __attribute__((ext_vector_type(4)));
typedef unsigned int u32x2 __attribute__((ext_vector_type(2)));

union H8 { f16x8 v; _Float16 h[8]; u32x4 u; };
union H4 { f16x4 v; u32x2 u; };
union H2 { fp16v2 h; unsigned int u; };

#define MFMA16(a, b, c) __builtin_amdgcn_mfma_f32_16x16x32_f16((a), (b), (c), 0, 0, 0)
#define MFMA32(a, b, c) __builtin_amdgcn_mfma_f32_32x32x16_f16((a), (b), (c), 0, 0, 0)

#define LOG2E 1.44269504088896340736f

// workspace byte offsets
#define WS_WP   0u          // 6 layers  : 6*65536 halves = 786432 B (32x32 pack)
#define WS_WPI  786432u     // 65536 halves = 131072 B (16x16 pack, k_atoms)
#define WS_WPJ  917504u     // 65536 halves = 131072 B
#define WS_WPR  1048576u    // 8192 halves  = 16384 B  (rbf+d, 32x32 pack)
#define WS_XH   1064960u    // 2097152 halves = 4194304 B
#define WS_AP   5259264u    // 2097152 fp16 = 4194304 B
#define WS_BP   9453568u    // 2097152 fp16 = 4194304 B
// total 13647872 B

// ---------------------------------------------------------------------------
__global__ __launch_bounds__(256) void k_prep(
    const float* __restrict__ x, const float* __restrict__ W_in,
    const float* __restrict__ Ws, const float* __restrict__ b_out,
    _Float16* __restrict__ wp, _Float16* __restrict__ wpi,
    _Float16* __restrict__ wpj, _Float16* __restrict__ wpr,
    _Float16* __restrict__ xh, float* __restrict__ out)
{
  int i = blockIdx.x * 256 + threadIdx.x;
  if (i < 2097152) { xh[i] = (_Float16)x[i]; return; }
  i -= 2097152;
  if (i < 393216) {  // 6 hidden layers, 32x32x16 A-fragment order (A = W^T)
    int m = i >> 16, r = i & 65535;
    int j = r & 7, lane = (r >> 3) & 63, kstep = (r >> 9) & 15, nt = (r >> 13) & 7;
    int k = kstep * 16 + (lane >> 5) * 8 + j, n = nt * 32 + (lane & 31);
    wp[i] = (_Float16)Ws[(m * 256 + k) * 256 + n];
    return;
  }
  i -= 393216;
  if (i < 65536) {   // W_in rows 0..255 (x_i part), 16x16 pack for k_atoms
    int j = i & 7, lane = (i >> 3) & 63, ks = (i >> 9) & 7, nt = (i >> 12) & 15;
    int k = ks * 32 + (lane >> 4) * 8 + j, n = nt * 16 + (lane & 15);
    wpi[i] = (_Float16)W_in[k * 256 + n];
    return;
  }
  i -= 65536;
  if (i < 65536) {   // W_in rows 256..511 (x_j part)
    int j = i & 7, lane = (i >> 3) & 63, ks = (i >> 9) & 7, nt = (i >> 12) & 15;
    int k = ks * 32 + (lane >> 4) * 8 + j, n = nt * 16 + (lane & 15);
    wpj[i] = (_Float16)W_in[(256 + k) * 256 + n];
    return;
  }
  i -= 65536;
  if (i < 8192) {    // rbf rows 512..531 + d row 532, 32x32x16 pack, K pad 32
    int j = i & 7, lane = (i >> 3) & 63, kstep = (i >> 9) & 1, nt = (i >> 10) & 7;
    int k = kstep * 16 + (lane >> 5) * 8 + j, n = nt * 32 + (lane & 31);
    float v = 0.0f;
    if (k < 20)       v = W_in[(512 + k) * 256 + n];
    else if (k == 20) v = W_in[532 * 256 + n];
    wpr[i] = (_Float16)v;
    return;
  }
  i -= 8192;
  if (i < 8192) out[i] = b_out[0];
}

// ---------------------------------------------------------------------------
// AP/BP: M=8192 atoms, K=256, N=256, fp16 packed output. BM=64 atoms/block,
// 4 waves (one 64-n slice each). blockIdx.y selects AP (with b_in) or BP.
__global__ __launch_bounds__(256) void k_atoms(
    const _Float16* __restrict__ xh,
    const _Float16* __restrict__ wpi, const _Float16* __restrict__ wpj,
    const float* __restrict__ b_in,
    _Float16* __restrict__ AP, _Float16* __restrict__ BP)
{
  const int tid = threadIdx.x;
  const int l = tid & 63, w = tid >> 6;
  const int g = l >> 4, c = l & 15;
  const int which = blockIdx.y;
  const _Float16* wpx = which ? wpj : wpi;
  _Float16* outp = which ? BP : AP;
  const int abase = blockIdx.x * 64;

  f32x4 acc[4][4];
#pragma unroll
  for (int nf = 0; nf < 4; ++nf)
#pragma unroll
    for (int at = 0; at < 4; ++at) acc[nf][at] = (f32x4)0.0f;

#pragma unroll
  for (int ks = 0; ks < 8; ++ks) {
    f16x8 a[4];
#pragma unroll
    for (int nf = 0; nf < 4; ++nf) {
      H8 t; t.u = *(const u32x4*)(wpx + (((w * 4 + nf) * 8 + ks) * 64 + l) * 8);
      a[nf] = t.v;
    }
#pragma unroll
    for (int at = 0; at < 4; ++at) {
      H8 b; b.u = *(const u32x4*)(xh + (abase + at * 16 + c) * 256 + ks * 32 + g * 8);
#pragma unroll
      for (int nf = 0; nf < 4; ++nf)
        acc[nf][at] = MFMA16(a[nf], b.v, acc[nf][at]);
    }
  }

#pragma unroll
  for (int nf = 0; nf < 4; ++nf) {
    const int n = w * 64 + nf * 16 + g * 4;
    f32x4 bias = (f32x4)0.0f;
    if (!which) bias = *(const f32x4*)(b_in + n);
#pragma unroll
    for (int at = 0; at < 4; ++at) {
      const int atom = abase + at * 16 + c;
      const f32x4 t = acc[nf][at] + bias;
      H2 lo, hi;
      lo.h = __builtin_amdgcn_cvt_pkrtz(t[0], t[1]);
      hi.h = __builtin_amdgcn_cvt_pkrtz(t[2], t[3]);
      u32x2 q; q[0] = lo.u; q[1] = hi.u;
      *(u32x2*)(outp + atom * 256 + n) = q;
    }
  }
}

// ---------------------------------------------------------------------------
// R14 fused edge pipeline, 32x32x16 MFMA. 128 edges/block, 512 threads =
// 8 waves = 2 edge-groups(64e) x 4 n-groups(64f); per wave 2x2 tiles of
// 32x32, acc2[2][2] f32x16 (64 AGPR). h tile [128e][256f] fp16, 64 KB,
// swizzle byte ^= (e5<<4), e5 = l&31. 2 barriers/layer, 2 blocks/CU.
__global__ __launch_bounds__(512, 2) void k_edges(
    const _Float16* __restrict__ AP, const _Float16* __restrict__ BP,
    const int* __restrict__ idx_i, const int* __restrict__ idx_j,
    const float* __restrict__ d_ij,
    const _Float16* __restrict__ wp, const _Float16* __restrict__ wpr,
    const float* __restrict__ bs, const float* __restrict__ W_out,
    float* __restrict__ out)
{
  __shared__ __align__(16) char hb[65536];
  __shared__ float d_lds[128];
  __shared__ int   ii_lds[128];
  __shared__ int   jj_lds[128];
  __shared__ float oacc[128];

  const int tid = threadIdx.x;
  const int l = tid & 63, w = tid >> 6;
  const int ge = w >> 2, gn = w & 3;
  const int e5 = l & 31, h5 = l >> 5;
  const int ebase = blockIdx.x * 128;
  const int we = ge * 64;         // wave's edge base (64 edges = 2 tiles)
  const int fb = gn * 64;         // wave's feature base (64 = 2 tiles of 32)
  const int sw = e5 << 4;         // 5-bit row swizzle

  if (tid < 128) {
    ii_lds[tid] = idx_i[ebase + tid];
    jj_lds[tid] = idx_j[ebase + tid];
    d_lds[tid]  = d_ij[ebase + tid];
    oacc[tid]   = 0.0f;
  }
  __syncthreads();

  f32x16 acc2[2][2];  // [ft][et] : (32 feat x 32 edge) tiles

  // ---- input layer: rbf(20)+d via two K=16 MFMA steps ----
  {
    const float STEP = 15.0f / 19.0f;
    const float C2 = (-0.5f / (STEP * STEP)) * LOG2E;
    f16x8 afr[2][2];   // [ft][kstep]
#pragma unroll
    for (int ft = 0; ft < 2; ++ft)
#pragma unroll
      for (int ks2 = 0; ks2 < 2; ++ks2) {
        H8 t; t.u = *(const u32x4*)(wpr + (((gn * 2 + ft) * 2 + ks2) * 64 + l) * 8);
        afr[ft][ks2] = t.v;
      }
#pragma unroll
    for (int et = 0; et < 2; ++et) {
      const float d = d_lds[we + et * 32 + e5];
      H8 bb[2];
#pragma unroll
      for (int ks2 = 0; ks2 < 2; ++ks2) {
#pragma unroll
        for (int j = 0; j < 8; ++j) {
          const int k = ks2 * 16 + h5 * 8 + j;
          float v = 0.0f;
          if (k < 20)       { const float df = d - (float)k * STEP; v = __builtin_amdgcn_exp2f(C2 * df * df); }
          else if (k == 20) { v = d; }
          bb[ks2].h[j] = (_Float16)v;
        }
      }
      const f32x16 z = (f32x16)0.0f;
#pragma unroll
      for (int ft = 0; ft < 2; ++ft)
        acc2[ft][et] = MFMA32(afr[ft][1], bb[1].v, MFMA32(afr[ft][0], bb[0].v, z));
    }
  }
  // h0 = pack(rbf acc) + AP[idx_i] + BP[idx_j]  (fp16 add) -> hb
#pragma unroll
  for (int ft = 0; ft < 2; ++ft) {
#pragma unroll
    for (int et = 0; et < 2; ++et) {
      const int el = we + et * 32 + e5;
#pragma unroll
      for (int q = 0; q < 4; ++q) {
        const int f4 = fb + ft * 32 + q * 8 + h5 * 4;   // 4 consecutive feats
        H4 pa, pb, s;
        pa.u = *(const u32x2*)(AP + ii_lds[el] * 256 + f4);
        pb.u = *(const u32x2*)(BP + jj_lds[el] * 256 + f4);
        H2 lo, hi;
        lo.h = __builtin_amdgcn_cvt_pkrtz(acc2[ft][et][q * 4 + 0], acc2[ft][et][q * 4 + 1]);
        hi.h = __builtin_amdgcn_cvt_pkrtz(acc2[ft][et][q * 4 + 2], acc2[ft][et][q * 4 + 3]);
        s.u[0] = lo.u; s.u[1] = hi.u;
        s.v = s.v + pa.v + pb.v;
        *(u32x2*)(hb + el * 512 + ((f4 * 2) ^ sw)) = s.u;
      }
    }
  }
  __syncthreads();

  // one fused hidden-layer matmul: acc = bias + (h @ W)^T
  auto mfma_layer = [&](const _Float16* wl, const float* brow) {
#pragma unroll
    for (int ft = 0; ft < 2; ++ft) {
#pragma unroll
      for (int q = 0; q < 4; ++q) {
        const f32x4 bq = *(const f32x4*)(brow + fb + ft * 32 + q * 8 + h5 * 4);
#pragma unroll
        for (int et = 0; et < 2; ++et) {
#pragma unroll
          for (int i2 = 0; i2 < 4; ++i2) acc2[ft][et][q * 4 + i2] = bq[i2];
        }
      }
    }
    __builtin_amdgcn_s_setprio(1);
#pragma unroll
    for (int kstep = 0; kstep < 16; ++kstep) {
      f16x8 a[2];
#pragma unroll
      for (int ft = 0; ft < 2; ++ft) {
        H8 t; t.u = *(const u32x4*)(wl + (((gn * 2 + ft) * 16 + kstep) * 64 + l) * 8);
        a[ft] = t.v;
      }
      const int o = (kstep * 32 + h5 * 16) ^ sw;
#pragma unroll
      for (int et = 0; et < 2; ++et) {
        const int el = we + et * 32 + e5;
        H8 b; b.u = *(const u32x4*)(hb + el * 512 + o);
#pragma unroll
        for (int ft = 0; ft < 2; ++ft)
          acc2[ft][et] = MFMA32(a[ft], b.v, acc2[ft][et]);
      }
    }
    __builtin_amdgcn_s_setprio(0);
  };

#pragma unroll 1
  for (int ly = 0; ly < 5; ++ly) {
    mfma_layer(wp + ly * 65536, bs + ly * 256);
    __syncthreads();   // all reads of hb done before in-place overwrite
#pragma unroll
    for (int ft = 0; ft < 2; ++ft) {
#pragma unroll
      for (int et = 0; et < 2; ++et) {
        const int el = we + et * 32 + e5;
#pragma unroll
        for (int q = 0; q < 4; ++q) {
          const int f4 = fb + ft * 32 + q * 8 + h5 * 4;
          float v0 = acc2[ft][et][q * 4 + 0], v1 = acc2[ft][et][q * 4 + 1];
          float v2 = acc2[ft][et][q * 4 + 2], v3 = acc2[ft][et][q * 4 + 3];
          v0 *= __builtin_amdgcn_rcpf(1.0f + __builtin_amdgcn_exp2f(v0 * -LOG2E));
          v1 *= __builtin_amdgcn_rcpf(1.0f + __builtin_amdgcn_exp2f(v1 * -LOG2E));
          v2 *= __builtin_amdgcn_rcpf(1.0f + __builtin_amdgcn_exp2f(v2 * -LOG2E));
          v3 *= __builtin_amdgcn_rcpf(1.0f + __builtin_amdgcn_exp2f(v3 * -LOG2E));
          H2 lo, hi;
          lo.h = __builtin_amdgcn_cvt_pkrtz(v0, v1);
          hi.h = __builtin_amdgcn_cvt_pkrtz(v2, v3);
          u32x2 qv; qv[0] = lo.u; qv[1] = hi.u;
          *(u32x2*)(hb + el * 512 + ((f4 * 2) ^ sw)) = qv;
        }
      }
    }
    __syncthreads();   // writes complete before next layer reads
  }

  // layer 6 (no activation): bias already seeded; fold W_out dot immediately
  mfma_layer(wp + 5 * 65536, bs + 5 * 256);
  float sum[2];
  sum[0] = 0.0f; sum[1] = 0.0f;
#pragma unroll
  for (int ft = 0; ft < 2; ++ft) {
#pragma unroll
    for (int q = 0; q < 4; ++q) {
      const f32x4 wo = *(const f32x4*)(W_out + fb + ft * 32 + q * 8 + h5 * 4);
#pragma unroll
      for (int et = 0; et < 2; ++et) {
        sum[et] += acc2[ft][et][q * 4 + 0] * wo[0] + acc2[ft][et][q * 4 + 1] * wo[1]
                 + acc2[ft][et][q * 4 + 2] * wo[2] + acc2[ft][et][q * 4 + 3] * wo[3];
      }
    }
  }
#pragma unroll
  for (int et = 0; et < 2; ++et) {
    float s = sum[et];
    s += __shfl_xor(s, 32, 64);          // combine the two k-half lanes
    if (l < 32) atomicAdd(&oacc[we + et * 32 + l], s);
  }
  __syncthreads();
  if (tid < 128) atomicAdd(out + ii_lds[tid], oacc[tid]);
}

// ---------------------------------------------------------------------------
extern "C" void kernel_launch(void* const* d_in, const int* in_sizes, int n_in,
                              void* d_out, int out_size, void* d_ws, size_t ws_size,
                              hipStream_t stream) {
  (void)in_sizes; (void)n_in; (void)out_size; (void)ws_size;
  const float* x     = (const float*)d_in[0];
  const float* d_ij  = (const float*)d_in[1];
  const int*   idx_i = (const int*)d_in[2];
  const int*   idx_j = (const int*)d_in[3];
  const float* W_in  = (const float*)d_in[4];
  const float* b_in  = (const float*)d_in[5];
  const float* Ws    = (const float*)d_in[6];
  const float* bs    = (const float*)d_in[7];
  const float* W_out = (const float*)d_in[8];
  const float* b_out = (const float*)d_in[9];
  float* out = (float*)d_out;
  char* ws = (char*)d_ws;

  _Float16* wp  = (_Float16*)(ws + WS_WP);
  _Float16* wpi = (_Float16*)(ws + WS_WPI);
  _Float16* wpj = (_Float16*)(ws + WS_WPJ);
  _Float16* wpr = (_Float16*)(ws + WS_WPR);
  _Float16* xh  = (_Float16*)(ws + WS_XH);
  _Float16* AP  = (_Float16*)(ws + WS_AP);
  _Float16* BP  = (_Float16*)(ws + WS_BP);

  hipLaunchKernelGGL(k_prep, dim3(10305), dim3(256), 0, stream,
                     x, W_in, Ws, b_out, wp, wpi, wpj, wpr, xh, out);
  hipLaunchKernelGGL(k_atoms, dim3(128, 2), dim3(256), 0, stream,
                     xh, wpi, wpj, b_in, AP, BP);
  hipLaunchKernelGGL(k_edges, dim3(2048), dim3(512), 0, stream,
                     AP, BP, idx_i, idx_j, d_ij, wp, wpr, bs, W_out, out);
}